// Round 11
// baseline (2658.995 us; speedup 1.0000x reference)
//
#include <hip/hip_runtime.h>

// LSTM fused persistent kernel for MI355X — round 11: zero-barrier free-running waves.
// 16 groups x 16 CUs; CU owns 32 hidden units; Wh fp16 in VGPRs.
// h published as 16B units {4 fp16, tag, pad} (single dwordx4 => atomic
// visibility). Each WAVE independently polls a 64-slice canary (1 unit/lane),
// then loads ALL 16 chunks (2 units/lane) straight into its MFMA A-fragments —
// embedded tags re-verified on the full load. No h in LDS, NO per-step
// __syncthreads. Triple-buffered global h (WAR by poll transitivity).

typedef __attribute__((ext_vector_type(8))) _Float16 f16x8;
typedef __attribute__((ext_vector_type(4))) float f32x4;
typedef __attribute__((ext_vector_type(4))) unsigned u32x4;

#define NTHR 256
constexpr int T_LEN = 512, EMB = 1024, HID = 512, NCLS = 10;
constexpr int GSIZE = 16;   // CUs per group
constexpr int NGRP  = 16;   // groups
constexpr int BPG   = 16;   // batches per group
constexpr int UPC   = 32;   // hidden units per CU
constexpr int COLS_PC = 128;
constexpr int NKT = 16;     // K tiles of 32 (HID=512)
constexpr int GUNITS  = GSIZE * 128;   // 16B-units per buffer per group (2048)
constexpr int GSTRIDE = 3 * GUNITS;    // units per group (3 buffers)

__device__ __forceinline__ float sigmf(float x)    { return 1.f / (1.f + __expf(-x)); }
__device__ __forceinline__ float tanhfast(float x) { return 1.f - 2.f / (__expf(2.f * x) + 1.f); }

// single 16B load with wait
__device__ __forceinline__ u32x4 ld16v(const u32x4* p) {
  u32x4 v;
  asm volatile("global_load_dwordx4 %0, %1, off sc0 sc1\n\ts_waitcnt vmcnt(0)"
               : "=v"(v) : "v"(p) : "memory");
  return v;
}
// issue two 16B loads (base, base+16B), no wait — caller drains vmcnt
__device__ __forceinline__ void ld_pair(const u32x4* p, u32x4& a, u32x4& b) {
  asm volatile("global_load_dwordx4 %0, %2, off sc0 sc1\n\t"
               "global_load_dwordx4 %1, %2, off offset:16 sc0 sc1"
               : "=&v"(a), "=&v"(b) : "v"(p) : "memory");
}
__device__ __forceinline__ void wait_vm0() {
  asm volatile("s_waitcnt vmcnt(0)" ::: "memory");
  __builtin_amdgcn_sched_barrier(0);          // rule #18: pin consumers after waitcnt
}
__device__ __forceinline__ void st16(u32x4* p, u32x4 v) {
  asm volatile("global_store_dwordx4 %0, %1, off sc0 sc1" :: "v"(p), "v"(v) : "memory");
}

__global__ __launch_bounds__(NTHR, 1) void lstm_fused(
    const int* __restrict__ xtok, const float* __restrict__ emb,
    const float* __restrict__ Wgx, const float* __restrict__ Wgh, const float* __restrict__ b_g,
    const float* __restrict__ Wix, const float* __restrict__ Wih, const float* __restrict__ b_i,
    const float* __restrict__ Wfx, const float* __restrict__ Wfh, const float* __restrict__ b_f,
    const float* __restrict__ Wox, const float* __restrict__ Woh, const float* __restrict__ b_o,
    const float* __restrict__ Wph, const float* __restrict__ b_p,
    float* __restrict__ out, u32x4* __restrict__ gb)
{
  const int tid  = threadIdx.x;
  const int wv   = tid >> 6;     // wave 0..3
  const int lane = tid & 63;
  const int q    = lane >> 4;    // lane quarter
  const int c    = lane & 15;
  const int wg   = blockIdx.x;
  const int grp  = wg >> 4;
  const int cu   = wg & 15;

  __shared__ __align__(16) _Float16 hstw[4][128];         // per-wave pack staging
  __shared__ unsigned char xl[BPG][T_LEN];                // 8 KB packed tokens
  __shared__ float projl[3][COLS_PC];                     // 1.5 KB
  __shared__ float projp[3][COLS_PC];                     // 1.5 KB partials

  // ---- pack this group's tokens into LDS (u8)
  for (int idx = tid; idx < BPG * T_LEN; idx += NTHR) {
    int bl = idx >> 9, tt = idx & (T_LEN - 1);
    xl[bl][tt] = (unsigned char)xtok[(grp * BPG + bl) * T_LEN + tt];
  }

  // ---- proj[v][cc] = b_gate[j] + emb[v] . Wx[:,gate,j], split over 2 halves of e
  {
    int cc = tid & 127, half = tid >> 7;
    int w2 = cc >> 5, nt = (cc >> 4) & 1, c2 = cc & 15;
    int gate = nt * 2 + (c2 >> 3);
    int j = cu * UPC + w2 * 8 + (c2 & 7);
    const float* Wx = gate == 0 ? Wgx : gate == 1 ? Wix : gate == 2 ? Wfx : Wox;
    const float* bb = gate == 0 ? b_g : gate == 1 ? b_i : gate == 2 ? b_f : b_o;
    int e0 = half * (EMB / 2);
    for (int v = 0; v < 3; ++v) {
      float s = half ? 0.f : bb[j];
      const float* er = emb + v * EMB + e0;
      const float* wp = Wx + e0 * HID + j;
      #pragma unroll 4
      for (int e = 0; e < EMB / 2; ++e) s = fmaf(er[e], wp[e * HID], s);
      (half ? projp : projl)[v][cc] = s;
    }
  }
  __syncthreads();
  for (int idx = tid; idx < 3 * COLS_PC; idx += NTHR) {
    int v = idx >> 7, cc = idx & 127;
    projl[v][cc] += projp[v][cc];
  }

  // ---- Wh B-fragments into registers (fp32 -> fp16), kept for all 512 steps.
  // (q, jj) -> k = 8q + jj, applied identically to A and B (HW perm cancels).
  f16x8 Bf[2][NKT];
  {
    int g0 = c >> 3;
    int j = cu * UPC + wv * 8 + (c & 7);
    #pragma unroll
    for (int nt = 0; nt < 2; ++nt) {
      int gate = nt * 2 + g0;
      const float* W = gate == 0 ? Wgh : gate == 1 ? Wih : gate == 2 ? Wfh : Woh;
      #pragma unroll
      for (int kt = 0; kt < NKT; ++kt) {
        f16x8 tmp;
        #pragma unroll
        for (int jj = 0; jj < 8; ++jj)
          tmp[jj] = (_Float16)W[(kt * 32 + q * 8 + jj) * HID + j];
        Bf[nt][kt] = tmp;
      }
    }
  }

  float cst[4] = {0.f, 0.f, 0.f, 0.f};     // c-state, rows q*4+r
  u32x4* ug = gb + grp * GSTRIDE;          // this group's 3 buffers (units)
  int br = 0;                              // read buffer == t % 3
  __syncthreads();                         // last barrier: init complete

  for (int t = 0; t < T_LEN; ++t) {
    f32x4 acc0 = {0.f, 0.f, 0.f, 0.f}, acc1 = {0.f, 0.f, 0.f, 0.f};
    if (t > 0) {
      // ---- canary poll (1 unit/lane covers all 64 producer slices), then
      // full 32-unit load with embedded-tag verification.
      const unsigned tagv = (unsigned)t;
      const u32x4* rb = ug + br * GUNITS;
      const u32x4* cp = rb + (lane >> 2) * 128 + (lane & 3) * 32;
      u32x4 ua[NKT], ub[NKT];
      for (;;) {
        u32x4 cv = ld16v(cp);
        if (!__all((int)(cv[2] == tagv))) { __builtin_amdgcn_s_sleep(1); continue; }
        #pragma unroll
        for (int i = 0; i < NKT; ++i)
          ld_pair(rb + i * 128 + 2 * lane, ua[i], ub[i]);
        wait_vm0();
        bool ok = true;
        #pragma unroll
        for (int i = 0; i < NKT; ++i)
          ok = ok && (ua[i][2] == tagv) && (ub[i][2] == tagv);
        if (__all((int)ok)) break;
        __builtin_amdgcn_s_sleep(1);
      }
      // ---- MFMA straight from loaded units: A-frag kt = fp16 [8*lane, +8) of
      // chunk kt = {ua[kt].xy, ub[kt].xy}
      #pragma unroll
      for (int kt = 0; kt < NKT; ++kt) {
        u32x4 av = {ua[kt][0], ua[kt][1], ub[kt][0], ub[kt][1]};
        f16x8 a;
        __builtin_memcpy(&a, &av, 16);
        acc0 = __builtin_amdgcn_mfma_f32_16x16x32_f16(a, Bf[0][kt], acc0, 0, 0, 0);
        acc1 = __builtin_amdgcn_mfma_f32_16x16x32_f16(a, Bf[1][kt], acc1, 0, 0, 0);
      }
    }

    // ---- nonlinearity + state update. C/D layout: col=lane&15, row=4q+reg.
    bool lo8 = (c < 8);
    #pragma unroll
    for (int r = 0; r < 4; ++r) {
      int bl = q * 4 + r;                     // batch row in tile
      int v = xl[bl][t];
      float p0 = acc0[r] + projl[v][wv * 32 + c];
      float p1 = acc1[r] + projl[v][wv * 32 + 16 + c];
      float p0x = __shfl_xor(p0, 8);
      float p1x = __shfl_xor(p1, 8);
      float gg = lo8 ? p0  : p0x;
      float ii = lo8 ? p0x : p0;
      float ff = lo8 ? p1  : p1x;
      float oo = lo8 ? p1x : p1;
      gg = tanhfast(gg); ii = sigmf(ii); ff = sigmf(ff); oo = sigmf(oo);
      float cn = fmaf(cst[r], ff, gg * ii);
      cst[r] = cn;
      float hv = tanhfast(cn) * oo;
      if (lo8) hstw[wv][bl * 8 + c] = (_Float16)hv;   // same-wave staging (proven)
    }

    // ---- publish: 32 units of {4 fp16, tag=t+1, 0} into buffer (t+1)%3
    int bw = (br + 1 == 3) ? 0 : br + 1;
    if (lane < 32) {
      const unsigned* hw = (const unsigned*)&hstw[wv][0];
      u32x4 pv = {hw[2 * lane], hw[2 * lane + 1], (unsigned)(t + 1), 0u};
      st16(ug + bw * GUNITS + cu * 128 + wv * 32 + lane, pv);
    }
    br = bw;
  }

  // ---- epilogue: poll final units (tag == 512, buffer 512%3 == 2), then
  // p = h_T @ W_ph + b_p ; log_softmax for batch grp*16+cu.
  if (wv == 0) {
    const u32x4* rb = ug + 2 * GUNITS;
    int kt = lane >> 2, qa = lane & 3;        // each lane: 8 consecutive j
    const u32x4* p = rb + kt * 128 + 2 * (qa * 16 + cu);
    u32x4 a, b;
    for (;;) {
      ld_pair(p, a, b);
      wait_vm0();
      bool ok = (a[2] == (unsigned)T_LEN) && (b[2] == (unsigned)T_LEN);
      if (__all((int)ok)) break;
      __builtin_amdgcn_s_sleep(1);
    }
    _Float16 hh[8];
    unsigned hw2[4] = {a[0], a[1], b[0], b[1]};
    __builtin_memcpy(&hh[0], &hw2[0], 16);
    float pc[NCLS];
    #pragma unroll
    for (int k2 = 0; k2 < NCLS; ++k2) pc[k2] = 0.f;
    int jbase = kt * 32 + qa * 8;
    #pragma unroll
    for (int jj = 0; jj < 8; ++jj) {
      float hv = (float)hh[jj];
      const float* wr = Wph + (jbase + jj) * NCLS;
      #pragma unroll
      for (int k2 = 0; k2 < NCLS; ++k2) pc[k2] = fmaf(hv, wr[k2], pc[k2]);
    }
    #pragma unroll
    for (int off = 32; off > 0; off >>= 1) {
      #pragma unroll
      for (int k2 = 0; k2 < NCLS; ++k2) pc[k2] += __shfl_down(pc[k2], off);
    }
    if (lane == 0) {
      float mx = -1e30f;
      #pragma unroll
      for (int k2 = 0; k2 < NCLS; ++k2) { pc[k2] += b_p[k2]; mx = fmaxf(mx, pc[k2]); }
      float se = 0.f;
      #pragma unroll
      for (int k2 = 0; k2 < NCLS; ++k2) se += __expf(pc[k2] - mx);
      float ls = mx + __logf(se);
      int b2 = grp * BPG + cu;
      #pragma unroll
      for (int k2 = 0; k2 < NCLS; ++k2) out[b2 * NCLS + k2] = pc[k2] - ls;
    }
  }
}

extern "C" void kernel_launch(void* const* d_in, const int* in_sizes, int n_in,
                              void* d_out, int out_size, void* d_ws, size_t ws_size,
                              hipStream_t stream) {
  (void)in_sizes; (void)n_in; (void)out_size; (void)ws_size;
  const int*   x   = (const int*)d_in[0];
  const float* emb = (const float*)d_in[1];
  const float* Wgx = (const float*)d_in[2];
  const float* Wgh = (const float*)d_in[3];
  const float* bg  = (const float*)d_in[4];
  const float* Wix = (const float*)d_in[5];
  const float* Wih = (const float*)d_in[6];
  const float* bi  = (const float*)d_in[7];
  const float* Wfx = (const float*)d_in[8];
  const float* Wfh = (const float*)d_in[9];
  const float* bfv = (const float*)d_in[10];
  const float* Wox = (const float*)d_in[11];
  const float* Woh = (const float*)d_in[12];
  const float* bo  = (const float*)d_in[13];
  const float* Wph = (const float*)d_in[14];
  const float* bp  = (const float*)d_in[15];
  float* out = (float*)d_out;

  // 16 groups x 3 buffers x 2048 units x 16B = 1.5 MB, tags cleared per launch
  (void)hipMemsetAsync(d_ws, 0, (size_t)NGRP * GSTRIDE * 16, stream);
  lstm_fused<<<dim3(NGRP * GSIZE), dim3(NTHR), 0, stream>>>(
      x, emb, Wgx, Wgh, bg, Wix, Wih, bi, Wfx, Wfh, bfv,
      Wox, Woh, bo, Wph, bp, out, (u32x4*)d_ws);
}

// Round 12
// 2225.974 us; speedup vs baseline: 1.1945x; 1.1945x over previous
//
#include <hip/hip_runtime.h>

// LSTM fused persistent kernel for MI355X — round 12: R10 protocol + 2 WGs/CU
// latency hiding. 32 groups x 8 batches x 16 CUs = 512 WGs (2 resident per CU;
// while one group's WG sleeps in its poll, the other computes). CU-slot owns 32
// hidden units; Wh fp16 in VGPRs. h published as 16B units {4 fp16, tag, pad}
// (single dwordx4 => atomic visibility); consumers poll their own data units.
// MFMA runs 16x16 with batch rows 8-15 hard-zero (pre-zeroed LDS slots) so the
// MFMA/NL/publish math is byte-identical to the proven R10 kernel.
// Triple-buffered global h (WAR by poll transitivity), ONE barrier per step.

typedef __attribute__((ext_vector_type(8))) _Float16 f16x8;
typedef __attribute__((ext_vector_type(4))) float f32x4;
typedef __attribute__((ext_vector_type(4))) unsigned u32x4;
typedef __attribute__((ext_vector_type(2))) unsigned u32x2;

#define NTHR 256
constexpr int T_LEN = 512, EMB = 1024, HID = 512, NCLS = 10;
constexpr int GSIZE = 16;   // CU-slots per group
constexpr int NGRP  = 32;   // groups (2 per physical CU)
constexpr int BPG   = 8;    // batches per group
constexpr int UPC   = 32;   // hidden units per CU-slot
constexpr int COLS_PC = 128;
constexpr int NKT = 16;     // K tiles of 32 (HID=512)
constexpr int GUNITS  = GSIZE * 64;    // 16B-units per buffer per group (1024)
constexpr int GSTRIDE = 3 * GUNITS;    // units per group (3 buffers)

__device__ __forceinline__ float sigmf(float x)    { return 1.f / (1.f + __expf(-x)); }
__device__ __forceinline__ float tanhfast(float x) { return 1.f - 2.f / (__expf(2.f * x) + 1.f); }

// issue two 16B loads (base, base+16B), no wait — caller drains vmcnt
__device__ __forceinline__ void ld_pair(const u32x4* p, u32x4& a, u32x4& b) {
  asm volatile("global_load_dwordx4 %0, %2, off sc0 sc1\n\t"
               "global_load_dwordx4 %1, %2, off offset:16 sc0 sc1"
               : "=&v"(a), "=&v"(b) : "v"(p) : "memory");
}
__device__ __forceinline__ void wait_vm0() {
  asm volatile("s_waitcnt vmcnt(0)" ::: "memory");
  __builtin_amdgcn_sched_barrier(0);          // rule #18: pin consumers after waitcnt
}
__device__ __forceinline__ void st16(u32x4* p, u32x4 v) {
  asm volatile("global_store_dwordx4 %0, %1, off sc0 sc1" :: "v"(p), "v"(v) : "memory");
}

__global__ __launch_bounds__(NTHR, 2) void lstm_fused(
    const int* __restrict__ xtok, const float* __restrict__ emb,
    const float* __restrict__ Wgx, const float* __restrict__ Wgh, const float* __restrict__ b_g,
    const float* __restrict__ Wix, const float* __restrict__ Wih, const float* __restrict__ b_i,
    const float* __restrict__ Wfx, const float* __restrict__ Wfh, const float* __restrict__ b_f,
    const float* __restrict__ Wox, const float* __restrict__ Woh, const float* __restrict__ b_o,
    const float* __restrict__ Wph, const float* __restrict__ b_p,
    float* __restrict__ out, u32x4* __restrict__ gb)
{
  const int tid  = threadIdx.x;
  const int wv   = tid >> 6;     // wave 0..3
  const int lane = tid & 63;
  const int q    = lane >> 4;    // lane quarter
  const int c    = lane & 15;
  const int wg   = blockIdx.x;
  const int grp  = wg >> 4;      // 0..31
  const int cu   = wg & 15;      // CU-slot within group

  __shared__ __align__(16) _Float16 h_lds[2][16 * 512];   // 2 x 16 KB, 16-row padded
  __shared__ __align__(16) _Float16 hstw[4][64];          // per-wave pack staging
  __shared__ unsigned char xl[BPG][T_LEN];                // 4 KB packed tokens
  __shared__ float projl[3][COLS_PC];                     // 1.5 KB
  __shared__ float projp[3][COLS_PC];                     // 1.5 KB partials

  // ---- pre-zero h_lds (rows 8-15 slots stay zero forever -> zero A-frags)
  {
    unsigned* hz = (unsigned*)&h_lds[0][0];
    #pragma unroll
    for (int i = 0; i < 32; ++i) hz[tid + i * NTHR] = 0u;
  }

  // ---- pack this group's tokens into LDS (u8)
  for (int idx = tid; idx < BPG * T_LEN; idx += NTHR) {
    int bl = idx >> 9, tt = idx & (T_LEN - 1);
    xl[bl][tt] = (unsigned char)xtok[(grp * BPG + bl) * T_LEN + tt];
  }

  // ---- proj[v][cc] = b_gate[j] + emb[v] . Wx[:,gate,j], split over 2 halves of e
  {
    int cc = tid & 127, half = tid >> 7;
    int w2 = cc >> 5, nt = (cc >> 4) & 1, c2 = cc & 15;
    int gate = nt * 2 + (c2 >> 3);
    int j = cu * UPC + w2 * 8 + (c2 & 7);
    const float* Wx = gate == 0 ? Wgx : gate == 1 ? Wix : gate == 2 ? Wfx : Wox;
    const float* bb = gate == 0 ? b_g : gate == 1 ? b_i : gate == 2 ? b_f : b_o;
    int e0 = half * (EMB / 2);
    for (int v = 0; v < 3; ++v) {
      float s = half ? 0.f : bb[j];
      const float* er = emb + v * EMB + e0;
      const float* wp = Wx + e0 * HID + j;
      #pragma unroll 4
      for (int e = 0; e < EMB / 2; ++e) s = fmaf(er[e], wp[e * HID], s);
      (half ? projp : projl)[v][cc] = s;
    }
  }
  __syncthreads();
  for (int idx = tid; idx < 3 * COLS_PC; idx += NTHR) {
    int v = idx >> 7, cc = idx & 127;
    projl[v][cc] += projp[v][cc];
  }

  // ---- Wh B-fragments into registers (fp32 -> fp16), kept for all 512 steps.
  // (q, jj) -> k = 8q + jj, applied identically to A and B (HW perm cancels).
  f16x8 Bf[2][NKT];
  {
    int g0 = c >> 3;
    int j = cu * UPC + wv * 8 + (c & 7);
    #pragma unroll
    for (int nt = 0; nt < 2; ++nt) {
      int gate = nt * 2 + g0;
      const float* W = gate == 0 ? Wgh : gate == 1 ? Wih : gate == 2 ? Wfh : Woh;
      #pragma unroll
      for (int kt = 0; kt < NKT; ++kt) {
        f16x8 tmp;
        #pragma unroll
        for (int jj = 0; jj < 8; ++jj)
          tmp[jj] = (_Float16)W[(kt * 32 + q * 8 + jj) * HID + j];
        Bf[nt][kt] = tmp;
      }
    }
  }

  float cst[4] = {0.f, 0.f, 0.f, 0.f};     // c-state, rows q*4+r (valid q<2)
  u32x4* ug = gb + grp * GSTRIDE;          // this group's 3 buffers (units)
  int br = 0;                              // read buffer == t % 3
  const int row = c;                       // A-row this lane covers (valid <8)
  const bool vrow = (row < 8);
  __syncthreads();

  for (int t = 0; t < T_LEN; ++t) {
    const int pl = t & 1;
    if (t > 0) {
      // ---- tagged-data poll: this wave's 4 chunks, rows<8 lanes only.
      // Global compact chunk layout: f' = 64q + 8row + jj -> unit q*16+row*2.
      const unsigned tagv = (unsigned)t;
      const u32x4* rb = ug + br * GUNITS;
      u32x4 ua[4], ubv[4];
      for (;;) {
        if (vrow) {
          #pragma unroll
          for (int i = 0; i < 4; ++i)
            ld_pair(rb + (wv * 4 + i) * 64 + q * 16 + row * 2, ua[i], ubv[i]);
          wait_vm0();
        }
        bool ok = true;
        if (vrow) {
          #pragma unroll
          for (int i = 0; i < 4; ++i)
            ok = ok && (ua[i][2] == tagv) && (ubv[i][2] == tagv);
        }
        if (__all((int)ok)) break;
        __builtin_amdgcn_s_sleep(1);
      }
      // ---- stage into 16-row-padded LDS image: f = 128q + 8row + jj
      if (vrow) {
        #pragma unroll
        for (int i = 0; i < 4; ++i) {
          int kt = wv * 4 + i;
          u32x2 lo = {ua[i][0], ua[i][1]};
          u32x2 hi = {ubv[i][0], ubv[i][1]};
          _Float16* dst = &h_lds[pl][kt * 512 + q * 128 + row * 8];
          *(u32x2*)dst       = lo;
          *(u32x2*)(dst + 4) = hi;
        }
      }
    }
    __syncthreads();   // the ONLY barrier per step

    // ---- gates tile: 8 batches (+8 zero rows) x 32 cols per wave, K=512
    f32x4 acc0 = {0.f, 0.f, 0.f, 0.f}, acc1 = {0.f, 0.f, 0.f, 0.f};
    if (t > 0) {
      const _Float16* hp = h_lds[pl];
      #pragma unroll
      for (int kt = 0; kt < NKT; ++kt) {
        f16x8 a = *(const f16x8*)(hp + kt * 512 + lane * 8);
        acc0 = __builtin_amdgcn_mfma_f32_16x16x32_f16(a, Bf[0][kt], acc0, 0, 0, 0);
        acc1 = __builtin_amdgcn_mfma_f32_16x16x32_f16(a, Bf[1][kt], acc1, 0, 0, 0);
      }
    }

    // ---- nonlinearity + state update (rows q*4+r < 8 => q<2 only).
    // C/D layout: col=lane&15, row=4q+reg. shfl partners lane^8 share q.
    if (q < 2) {
      bool lo8 = (c < 8);
      #pragma unroll
      for (int r = 0; r < 4; ++r) {
        int bl = q * 4 + r;                   // batch row in tile (0..7)
        int v = xl[bl][t];
        float p0 = acc0[r] + projl[v][wv * 32 + c];
        float p1 = acc1[r] + projl[v][wv * 32 + 16 + c];
        float p0x = __shfl_xor(p0, 8);
        float p1x = __shfl_xor(p1, 8);
        float gg = lo8 ? p0  : p0x;
        float ii = lo8 ? p0x : p0;
        float ff = lo8 ? p1  : p1x;
        float oo = lo8 ? p1x : p1;
        gg = tanhfast(gg); ii = sigmf(ii); ff = sigmf(ff); oo = sigmf(oo);
        float cn = fmaf(cst[r], ff, gg * ii);
        cst[r] = cn;
        float hv = tanhfast(cn) * oo;
        if (lo8) hstw[wv][bl * 8 + c] = (_Float16)hv;  // [8 rows][8 units]
      }
    }

    // ---- publish: 16 units of {4 fp16, tag=t+1, 0} into buffer (t+1)%3
    int bw = (br + 1 == 3) ? 0 : br + 1;
    if (lane < 16) {
      const unsigned* hw = (const unsigned*)&hstw[wv][0];
      u32x4 pv = {hw[2 * lane], hw[2 * lane + 1], (unsigned)(t + 1), 0u};
      st16(ug + bw * GUNITS + cu * 64 + wv * 16 + lane, pv);
    }
    br = bw;
  }

  // ---- epilogue: WGs cu<8, wave0 handle batch grp*8+cu. Buffer 512%3 == 2.
  if (wv == 0 && cu < 8) {
    const u32x4* rb = ug + 2 * GUNITS;
    int kt = lane >> 2, qa = lane & 3;        // lane covers j in [lane*8, +8)
    const u32x4* p = rb + kt * 64 + qa * 16 + cu * 2;
    u32x4 a, b;
    for (;;) {
      ld_pair(p, a, b);
      wait_vm0();
      bool ok = (a[2] == (unsigned)T_LEN) && (b[2] == (unsigned)T_LEN);
      if (__all((int)ok)) break;
      __builtin_amdgcn_s_sleep(1);
    }
    _Float16 hh[8];
    unsigned hw2[4] = {a[0], a[1], b[0], b[1]};
    __builtin_memcpy(&hh[0], &hw2[0], 16);
    float pc[NCLS];
    #pragma unroll
    for (int k2 = 0; k2 < NCLS; ++k2) pc[k2] = 0.f;
    int jbase = kt * 32 + qa * 8;
    #pragma unroll
    for (int jj = 0; jj < 8; ++jj) {
      float hv = (float)hh[jj];
      const float* wr = Wph + (jbase + jj) * NCLS;
      #pragma unroll
      for (int k2 = 0; k2 < NCLS; ++k2) pc[k2] = fmaf(hv, wr[k2], pc[k2]);
    }
    #pragma unroll
    for (int off = 32; off > 0; off >>= 1) {
      #pragma unroll
      for (int k2 = 0; k2 < NCLS; ++k2) pc[k2] += __shfl_down(pc[k2], off);
    }
    if (lane == 0) {
      float mx = -1e30f;
      #pragma unroll
      for (int k2 = 0; k2 < NCLS; ++k2) { pc[k2] += b_p[k2]; mx = fmaxf(mx, pc[k2]); }
      float se = 0.f;
      #pragma unroll
      for (int k2 = 0; k2 < NCLS; ++k2) se += __expf(pc[k2] - mx);
      float ls = mx + __logf(se);
      int b2 = grp * BPG + cu;
      #pragma unroll
      for (int k2 = 0; k2 < NCLS; ++k2) out[b2 * NCLS + k2] = pc[k2] - ls;
    }
  }
}

extern "C" void kernel_launch(void* const* d_in, const int* in_sizes, int n_in,
                              void* d_out, int out_size, void* d_ws, size_t ws_size,
                              hipStream_t stream) {
  (void)in_sizes; (void)n_in; (void)out_size; (void)ws_size;
  const int*   x   = (const int*)d_in[0];
  const float* emb = (const float*)d_in[1];
  const float* Wgx = (const float*)d_in[2];
  const float* Wgh = (const float*)d_in[3];
  const float* bg  = (const float*)d_in[4];
  const float* Wix = (const float*)d_in[5];
  const float* Wih = (const float*)d_in[6];
  const float* bi  = (const float*)d_in[7];
  const float* Wfx = (const float*)d_in[8];
  const float* Wfh = (const float*)d_in[9];
  const float* bfv = (const float*)d_in[10];
  const float* Wox = (const float*)d_in[11];
  const float* Woh = (const float*)d_in[12];
  const float* bo  = (const float*)d_in[13];
  const float* Wph = (const float*)d_in[14];
  const float* bp  = (const float*)d_in[15];
  float* out = (float*)d_out;

  // 32 groups x 3 buffers x 1024 units x 16B = 1.5 MB, tags cleared per launch
  (void)hipMemsetAsync(d_ws, 0, (size_t)NGRP * GSTRIDE * 16, stream);
  lstm_fused<<<dim3(NGRP * GSIZE), dim3(NTHR), 0, stream>>>(
      x, emb, Wgx, Wgh, bg, Wix, Wih, bi, Wfx, Wfh, bfv,
      Wox, Woh, bo, Wph, bp, out, (u32x4*)d_ws);
}

// Round 13
// 1760.067 us; speedup vs baseline: 1.5107x; 1.2647x over previous
//
#include <hip/hip_runtime.h>

// LSTM fused persistent kernel for MI355X — round 13: R10 + K-split MFMA.
// 16 groups x 16 CUs; CU owns 32 hidden units; Wh fp16 in VGPRs (Bf[8][4]).
// h published as 16B units {4 fp16, tag, pad} (single dwordx4 => atomic
// visibility). Wave wv polls ONLY its 4 producer CUs' chunks (= k-slices
// 4wv..4wv+3) and immediately computes K-partial MFMAs for ALL 8 n-tiles from
// registers — straggler wait overlaps compute. Partials reduced via LDS
// (double-buffered, ONE barrier/step), then NL + publish as in R10.
// Triple-buffered global h (WAR by poll transitivity).

typedef __attribute__((ext_vector_type(8))) _Float16 f16x8;
typedef __attribute__((ext_vector_type(4))) float f32x4;
typedef __attribute__((ext_vector_type(4))) unsigned u32x4;

#define NTHR 256
constexpr int T_LEN = 512, EMB = 1024, HID = 512, NCLS = 10;
constexpr int GSIZE = 16;   // CUs per group
constexpr int NGRP  = 16;   // groups
constexpr int BPG   = 16;   // batches per group
constexpr int UPC   = 32;   // hidden units per CU
constexpr int COLS_PC = 128;
constexpr int GUNITS  = GSIZE * 128;   // 16B-units per buffer per group (2048)
constexpr int GSTRIDE = 3 * GUNITS;    // units per group (3 buffers)

__device__ __forceinline__ float sigmf(float x)    { return 1.f / (1.f + __expf(-x)); }
__device__ __forceinline__ float tanhfast(float x) { return 1.f - 2.f / (__expf(2.f * x) + 1.f); }

// issue two 16B loads (base, base+16B), no wait — caller drains vmcnt
__device__ __forceinline__ void ld_pair(const u32x4* p, u32x4& a, u32x4& b) {
  asm volatile("global_load_dwordx4 %0, %2, off sc0 sc1\n\t"
               "global_load_dwordx4 %1, %2, off offset:16 sc0 sc1"
               : "=&v"(a), "=&v"(b) : "v"(p) : "memory");
}
__device__ __forceinline__ void wait_vm0() {
  asm volatile("s_waitcnt vmcnt(0)" ::: "memory");
  __builtin_amdgcn_sched_barrier(0);          // rule #18: pin consumers after waitcnt
}
__device__ __forceinline__ void st16(u32x4* p, u32x4 v) {
  asm volatile("global_store_dwordx4 %0, %1, off sc0 sc1" :: "v"(p), "v"(v) : "memory");
}

__global__ __launch_bounds__(NTHR, 1) void lstm_fused(
    const int* __restrict__ xtok, const float* __restrict__ emb,
    const float* __restrict__ Wgx, const float* __restrict__ Wgh, const float* __restrict__ b_g,
    const float* __restrict__ Wix, const float* __restrict__ Wih, const float* __restrict__ b_i,
    const float* __restrict__ Wfx, const float* __restrict__ Wfh, const float* __restrict__ b_f,
    const float* __restrict__ Wox, const float* __restrict__ Woh, const float* __restrict__ b_o,
    const float* __restrict__ Wph, const float* __restrict__ b_p,
    float* __restrict__ out, u32x4* __restrict__ gb)
{
  const int tid  = threadIdx.x;
  const int wv   = tid >> 6;     // wave 0..3
  const int lane = tid & 63;
  const int q    = lane >> 4;    // lane quarter
  const int c    = lane & 15;
  const int wg   = blockIdx.x;
  const int grp  = wg >> 4;
  const int cu   = wg & 15;

  __shared__ __align__(16) f32x4 pacc[2][4][8][64];       // 64 KB partial sums
  __shared__ __align__(16) _Float16 hstw[4][128];         // per-wave pack staging
  __shared__ unsigned char xl[BPG][T_LEN];                // 8 KB packed tokens
  __shared__ float projl[3][COLS_PC];                     // 1.5 KB
  __shared__ float projp[3][COLS_PC];                     // 1.5 KB partials

  // ---- pack this group's tokens into LDS (u8)
  for (int idx = tid; idx < BPG * T_LEN; idx += NTHR) {
    int bl = idx >> 9, tt = idx & (T_LEN - 1);
    xl[bl][tt] = (unsigned char)xtok[(grp * BPG + bl) * T_LEN + tt];
  }

  // ---- proj[v][cc] = b_gate[j] + emb[v] . Wx[:,gate,j], split over 2 halves of e
  {
    int cc = tid & 127, half = tid >> 7;
    int w2 = cc >> 5, nt = (cc >> 4) & 1, c2 = cc & 15;
    int gate = nt * 2 + (c2 >> 3);
    int j = cu * UPC + w2 * 8 + (c2 & 7);
    const float* Wx = gate == 0 ? Wgx : gate == 1 ? Wix : gate == 2 ? Wfx : Wox;
    const float* bb = gate == 0 ? b_g : gate == 1 ? b_i : gate == 2 ? b_f : b_o;
    int e0 = half * (EMB / 2);
    for (int v = 0; v < 3; ++v) {
      float s = half ? 0.f : bb[j];
      const float* er = emb + v * EMB + e0;
      const float* wp = Wx + e0 * HID + j;
      #pragma unroll 4
      for (int e = 0; e < EMB / 2; ++e) s = fmaf(er[e], wp[e * HID], s);
      (half ? projp : projl)[v][cc] = s;
    }
  }
  __syncthreads();
  for (int idx = tid; idx < 3 * COLS_PC; idx += NTHR) {
    int v = idx >> 7, cc = idx & 127;
    projl[v][cc] += projp[v][cc];
  }

  // ---- Wh B-fragments, K-split: wave wv holds k-slices 4wv..4wv+3 for ALL
  // 8 n-tiles. Col n*16+c: gate = (n&1)*2 + (c>>3), j = cu*32 + (n>>1)*8 + (c&7)
  // (verified: n = wv*2+{0,1} reproduces the proven nt0/nt1 mapping).
  // Row (k): (wv*4+kk)*32 + q*8 + jj — (q,jj)->k convention matches A side.
  f16x8 Bf[8][4];
  {
    int g0 = c >> 3;
    #pragma unroll
    for (int n = 0; n < 8; ++n) {
      int gate = (n & 1) * 2 + g0;
      int j = cu * UPC + (n >> 1) * 8 + (c & 7);
      const float* W = gate == 0 ? Wgh : gate == 1 ? Wih : gate == 2 ? Wfh : Woh;
      #pragma unroll
      for (int kk = 0; kk < 4; ++kk) {
        f16x8 tmp;
        #pragma unroll
        for (int jj = 0; jj < 8; ++jj)
          tmp[jj] = (_Float16)W[((wv * 4 + kk) * 32 + q * 8 + jj) * HID + j];
        Bf[n][kk] = tmp;
      }
    }
  }

  float cst[4] = {0.f, 0.f, 0.f, 0.f};     // c-state, rows q*4+r
  u32x4* ug = gb + grp * GSTRIDE;          // this group's 3 buffers (units)
  int br = 0;                              // read buffer == t % 3
  __syncthreads();

  for (int t = 0; t < T_LEN; ++t) {
    const int pl = t & 1;
    f32x4 accp[8] = {{0.f,0.f,0.f,0.f},{0.f,0.f,0.f,0.f},{0.f,0.f,0.f,0.f},{0.f,0.f,0.f,0.f},
                     {0.f,0.f,0.f,0.f},{0.f,0.f,0.f,0.f},{0.f,0.f,0.f,0.f},{0.f,0.f,0.f,0.f}};
    if (t > 0) {
      // ---- poll ONLY this wave's 4 producer chunks (CUs 4wv..4wv+3)
      const unsigned tagv = (unsigned)t;
      const u32x4* rb = ug + br * GUNITS;
      u32x4 ua[4], ub[4];
      for (;;) {
        #pragma unroll
        for (int i = 0; i < 4; ++i)
          ld_pair(rb + (wv * 4 + i) * 128 + 2 * lane, ua[i], ub[i]);
        wait_vm0();
        bool ok = true;
        #pragma unroll
        for (int i = 0; i < 4; ++i)
          ok = ok && (ua[i][2] == tagv) && (ub[i][2] == tagv);
        if (__all((int)ok)) break;
        __builtin_amdgcn_s_sleep(1);
      }
      // ---- K-partial MFMAs straight from registers (A-frag bytes proven in R11)
      #pragma unroll
      for (int kk = 0; kk < 4; ++kk) {
        u32x4 av = {ua[kk][0], ua[kk][1], ub[kk][0], ub[kk][1]};
        f16x8 a;
        __builtin_memcpy(&a, &av, 16);
        #pragma unroll
        for (int n = 0; n < 8; ++n)
          accp[n] = __builtin_amdgcn_mfma_f32_16x16x32_f16(a, Bf[n][kk], accp[n], 0, 0, 0);
      }
    }
    // ---- write partials, reduce across waves (double-buffered pacc)
    #pragma unroll
    for (int n = 0; n < 8; ++n) pacc[pl][wv][n][lane] = accp[n];
    __syncthreads();   // the ONLY barrier per step
    f32x4 p00 = pacc[pl][0][wv * 2][lane],     p01 = pacc[pl][1][wv * 2][lane];
    f32x4 p02 = pacc[pl][2][wv * 2][lane],     p03 = pacc[pl][3][wv * 2][lane];
    f32x4 p10 = pacc[pl][0][wv * 2 + 1][lane], p11 = pacc[pl][1][wv * 2 + 1][lane];
    f32x4 p12 = pacc[pl][2][wv * 2 + 1][lane], p13 = pacc[pl][3][wv * 2 + 1][lane];
    f32x4 acc0 = (p00 + p01) + (p02 + p03);
    f32x4 acc1 = (p10 + p11) + (p12 + p13);

    // ---- nonlinearity + state update. C/D layout: col=lane&15, row=4q+reg.
    bool lo8 = (c < 8);
    #pragma unroll
    for (int r = 0; r < 4; ++r) {
      int bl = q * 4 + r;                     // batch row in tile
      int v = xl[bl][t];
      float p0 = acc0[r] + projl[v][wv * 32 + c];
      float p1 = acc1[r] + projl[v][wv * 32 + 16 + c];
      float p0x = __shfl_xor(p0, 8);
      float p1x = __shfl_xor(p1, 8);
      float gg = lo8 ? p0  : p0x;
      float ii = lo8 ? p0x : p0;
      float ff = lo8 ? p1  : p1x;
      float oo = lo8 ? p1x : p1;
      gg = tanhfast(gg); ii = sigmf(ii); ff = sigmf(ff); oo = sigmf(oo);
      float cn = fmaf(cst[r], ff, gg * ii);
      cst[r] = cn;
      float hv = tanhfast(cn) * oo;
      if (lo8) hstw[wv][bl * 8 + c] = (_Float16)hv;   // same-wave staging (proven)
    }

    // ---- publish: 32 units of {4 fp16, tag=t+1, 0} into buffer (t+1)%3
    int bw = (br + 1 == 3) ? 0 : br + 1;
    if (lane < 32) {
      const unsigned* hw = (const unsigned*)&hstw[wv][0];
      u32x4 pv = {hw[2 * lane], hw[2 * lane + 1], (unsigned)(t + 1), 0u};
      st16(ug + bw * GUNITS + cu * 128 + wv * 32 + lane, pv);
    }
    br = bw;
  }

  // ---- epilogue: poll final units (tag == 512, buffer 512%3 == 2), then
  // p = h_T @ W_ph + b_p ; log_softmax for batch grp*16+cu.
  if (wv == 0) {
    const u32x4* rb = ug + 2 * GUNITS;
    int kt = lane >> 2, qa = lane & 3;        // each lane: 8 consecutive j
    const u32x4* p = rb + kt * 128 + 2 * (qa * 16 + cu);
    u32x4 a, b;
    for (;;) {
      ld_pair(p, a, b);
      wait_vm0();
      bool ok = (a[2] == (unsigned)T_LEN) && (b[2] == (unsigned)T_LEN);
      if (__all((int)ok)) break;
      __builtin_amdgcn_s_sleep(1);
    }
    _Float16 hh[8];
    unsigned hw2[4] = {a[0], a[1], b[0], b[1]};
    __builtin_memcpy(&hh[0], &hw2[0], 16);
    float pc[NCLS];
    #pragma unroll
    for (int k2 = 0; k2 < NCLS; ++k2) pc[k2] = 0.f;
    int jbase = kt * 32 + qa * 8;
    #pragma unroll
    for (int jj = 0; jj < 8; ++jj) {
      float hv = (float)hh[jj];
      const float* wr = Wph + (jbase + jj) * NCLS;
      #pragma unroll
      for (int k2 = 0; k2 < NCLS; ++k2) pc[k2] = fmaf(hv, wr[k2], pc[k2]);
    }
    #pragma unroll
    for (int off = 32; off > 0; off >>= 1) {
      #pragma unroll
      for (int k2 = 0; k2 < NCLS; ++k2) pc[k2] += __shfl_down(pc[k2], off);
    }
    if (lane == 0) {
      float mx = -1e30f;
      #pragma unroll
      for (int k2 = 0; k2 < NCLS; ++k2) { pc[k2] += b_p[k2]; mx = fmaxf(mx, pc[k2]); }
      float se = 0.f;
      #pragma unroll
      for (int k2 = 0; k2 < NCLS; ++k2) se += __expf(pc[k2] - mx);
      float ls = mx + __logf(se);
      int b2 = grp * BPG + cu;
      #pragma unroll
      for (int k2 = 0; k2 < NCLS; ++k2) out[b2 * NCLS + k2] = pc[k2] - ls;
    }
  }
}

extern "C" void kernel_launch(void* const* d_in, const int* in_sizes, int n_in,
                              void* d_out, int out_size, void* d_ws, size_t ws_size,
                              hipStream_t stream) {
  (void)in_sizes; (void)n_in; (void)out_size; (void)ws_size;
  const int*   x   = (const int*)d_in[0];
  const float* emb = (const float*)d_in[1];
  const float* Wgx = (const float*)d_in[2];
  const float* Wgh = (const float*)d_in[3];
  const float* bg  = (const float*)d_in[4];
  const float* Wix = (const float*)d_in[5];
  const float* Wih = (const float*)d_in[6];
  const float* bi  = (const float*)d_in[7];
  const float* Wfx = (const float*)d_in[8];
  const float* Wfh = (const float*)d_in[9];
  const float* bfv = (const float*)d_in[10];
  const float* Wox = (const float*)d_in[11];
  const float* Woh = (const float*)d_in[12];
  const float* bo  = (const float*)d_in[13];
  const float* Wph = (const float*)d_in[14];
  const float* bp  = (const float*)d_in[15];
  float* out = (float*)d_out;

  // 16 groups x 3 buffers x 2048 units x 16B = 1.5 MB, tags cleared per launch
  (void)hipMemsetAsync(d_ws, 0, (size_t)NGRP * GSTRIDE * 16, stream);
  lstm_fused<<<dim3(NGRP * GSIZE), dim3(NTHR), 0, stream>>>(
      x, emb, Wgx, Wgh, bg, Wix, Wih, bi, Wfx, Wfh, bfv,
      Wox, Woh, bo, Wph, bp, out, (u32x4*)d_ws);
}